// Round 1
// baseline (117.674 us; speedup 1.0000x reference)
//
#include <hip/hip_runtime.h>
#include <hip/hip_bf16.h>
#include <math.h>

typedef __bf16 bf16_t;
typedef __bf16 bf16x8 __attribute__((ext_vector_type(8)));
typedef float floatx4 __attribute__((ext_vector_type(4)));
typedef unsigned int u32;

#define NHEAD 16

// async global->LDS, 16B per lane. Dest must be wave-uniform base + lane*16.
__device__ __forceinline__ void gload_lds16(const void* g, void* l) {
    __builtin_amdgcn_global_load_lds((const __attribute__((address_space(1))) u32*)g,
                                     (__attribute__((address_space(3))) u32*)l, 16, 0, 0);
}

// ---------------- fp32 -> bf16 convert, 8 elems/thread ----------------
__global__ __launch_bounds__(256) void k_cvt(const float* __restrict__ src,
                                             bf16_t* __restrict__ dst, int n) {
    int i = (blockIdx.x * 256 + threadIdx.x) * 8;
    if (i >= n) return;
    float4 a = *(const float4*)(src + i);
    float4 b = *(const float4*)(src + i + 4);
    bf16x8 o;
    o[0]=(bf16_t)a.x; o[1]=(bf16_t)a.y; o[2]=(bf16_t)a.z; o[3]=(bf16_t)a.w;
    o[4]=(bf16_t)b.x; o[5]=(bf16_t)b.y; o[6]=(bf16_t)b.z; o[7]=(bf16_t)b.w;
    *(bf16x8*)(dst + i) = o;
}

// ---------------- RoPE cos/sin table: [2048][32] each ----------------
__global__ __launch_bounds__(256) void k_rope_table(float* __restrict__ ct,
                                                    float* __restrict__ st) {
    int idx = blockIdx.x * 256 + threadIdx.x;   // 65536 = 2048*32
    int s = idx >> 5, i = idx & 31;
    float e = (float)(2 * i) / 64.0f;
    float invf = 1.0f / powf(10000.0f, e);
    float ang = (float)s * invf;
    ct[idx] = cosf(ang);
    st[idx] = sinf(ang);
}

// ---------------- QKV GEMM: out[m,n] = sum_k A[m,k]*W[n,k] + b[n] ----------------
// 128x128 tile, BK=32, 4 waves, 16x16x32 bf16 MFMA (m97 structure).
// Epilogue: head layout [B,H,S,64] bf16, with RoPE for Q,K (id<2).
__global__ __launch_bounds__(256,2) void k_gemm_qkv(
    const bf16_t* __restrict__ Xq, const bf16_t* __restrict__ Xk, const bf16_t* __restrict__ Xv,
    const bf16_t* __restrict__ Wqb, const bf16_t* __restrict__ Wkb, const bf16_t* __restrict__ Wvb,
    const float* __restrict__ bq, const float* __restrict__ bk, const float* __restrict__ bv,
    bf16_t* __restrict__ Qr, bf16_t* __restrict__ Kr, bf16_t* __restrict__ Vh,
    const float* __restrict__ ct, const float* __restrict__ st)
{
    __shared__ bf16_t As[128*32];
    __shared__ bf16_t Bs[128*32];
    int id  = blockIdx.x >> 8;          // 0=Q 1=K 2=V
    int bid = blockIdx.x & 255;
    const bf16_t* A   = (id==0) ? Xq  : (id==1) ? Xk  : Xv;
    const bf16_t* Wt  = (id==0) ? Wqb : (id==1) ? Wkb : Wvb;
    const float*  bias= (id==0) ? bq  : (id==1) ? bk  : bv;
    bf16_t* out = (id==0) ? Qr : (id==1) ? Kr : Vh;
    bool do_rope = (id < 2);

    int bm = (bid >> 3) << 7;           // M=4096 -> 32 row tiles
    int bn = (bid & 7) << 7;            // N=1024 -> 8 col tiles
    int tid = threadIdx.x;
    int l = tid & 63, wid = tid >> 6;
    int wr = wid >> 1, wc = wid & 1;
    int lane16 = l & 15, hi8 = (l >> 4) << 3;

    floatx4 acc[4][4];
    #pragma unroll
    for (int i = 0; i < 4; ++i)
        #pragma unroll
        for (int j = 0; j < 4; ++j) acc[i][j] = (floatx4){0.f,0.f,0.f,0.f};

    for (int k0 = 0; k0 < 1024; k0 += 32) {
        #pragma unroll
        for (int i2 = 0; i2 < 2; ++i2) {
            int c = tid + (i2 << 8);
            int row = c >> 2, col = (c & 3) << 3;
            gload_lds16(A  + ((size_t)(bm + row) << 10) + k0 + col, &As[c << 3]);
            gload_lds16(Wt + ((size_t)(bn + row) << 10) + k0 + col, &Bs[c << 3]);
        }
        __syncthreads();
        bf16x8 af[4], bfr[4];
        #pragma unroll
        for (int i = 0; i < 4; ++i)
            af[i]  = *(const bf16x8*)&As[((wr<<6) + (i<<4) + lane16)*32 + hi8];
        #pragma unroll
        for (int j = 0; j < 4; ++j)
            bfr[j] = *(const bf16x8*)&Bs[((wc<<6) + (j<<4) + lane16)*32 + hi8];
        #pragma unroll
        for (int i = 0; i < 4; ++i)
            #pragma unroll
            for (int j = 0; j < 4; ++j)
                acc[i][j] = __builtin_amdgcn_mfma_f32_16x16x32_bf16(af[i], bfr[j], acc[i][j], 0, 0, 0);
        __syncthreads();
    }

    int h = (bn + (wc<<6)) >> 6;        // head index (64-wide wave tile == one head)
    #pragma unroll
    for (int i = 0; i < 4; ++i) {
        #pragma unroll
        for (int r = 0; r < 4; ++r) {
            int m  = bm + (wr<<6) + (i<<4) + ((l>>4)<<2) + r;
            int b_ = m >> 11, s_ = m & 2047;
            size_t ob = ((((size_t)(b_*NHEAD + h)) << 11) + s_) << 6;
            if (do_rope) {
                #pragma unroll
                for (int j = 0; j < 2; ++j) {
                    int d = (j<<4) + lane16;                 // 0..31
                    float lo = acc[i][j][r]   + bias[bn + (wc<<6) + d];
                    float hv = acc[i][j+2][r] + bias[bn + (wc<<6) + d + 32];
                    float c = ct[(s_<<5) + d], sn = st[(s_<<5) + d];
                    out[ob + d]      = (bf16_t)(lo*c - hv*sn);
                    out[ob + d + 32] = (bf16_t)(hv*c + lo*sn);
                }
            } else {
                #pragma unroll
                for (int j = 0; j < 4; ++j) {
                    int d = (j<<4) + lane16;
                    out[ob + d] = (bf16_t)(acc[i][j][r] + bias[bn + (wc<<6) + d]);
                }
            }
        }
    }
}

// ---------------- O GEMM: fp32 [4096][1024] output ----------------
__global__ __launch_bounds__(256,2) void k_gemm_o(
    const bf16_t* __restrict__ A, const bf16_t* __restrict__ Wt,
    const float* __restrict__ bias, float* __restrict__ out)
{
    __shared__ bf16_t As[128*32];
    __shared__ bf16_t Bs[128*32];
    int bid = blockIdx.x;
    int bm = (bid >> 3) << 7;
    int bn = (bid & 7) << 7;
    int tid = threadIdx.x;
    int l = tid & 63, wid = tid >> 6;
    int wr = wid >> 1, wc = wid & 1;
    int lane16 = l & 15, hi8 = (l >> 4) << 3;

    floatx4 acc[4][4];
    #pragma unroll
    for (int i = 0; i < 4; ++i)
        #pragma unroll
        for (int j = 0; j < 4; ++j) acc[i][j] = (floatx4){0.f,0.f,0.f,0.f};

    for (int k0 = 0; k0 < 1024; k0 += 32) {
        #pragma unroll
        for (int i2 = 0; i2 < 2; ++i2) {
            int c = tid + (i2 << 8);
            int row = c >> 2, col = (c & 3) << 3;
            gload_lds16(A  + ((size_t)(bm + row) << 10) + k0 + col, &As[c << 3]);
            gload_lds16(Wt + ((size_t)(bn + row) << 10) + k0 + col, &Bs[c << 3]);
        }
        __syncthreads();
        bf16x8 af[4], bfr[4];
        #pragma unroll
        for (int i = 0; i < 4; ++i)
            af[i]  = *(const bf16x8*)&As[((wr<<6) + (i<<4) + lane16)*32 + hi8];
        #pragma unroll
        for (int j = 0; j < 4; ++j)
            bfr[j] = *(const bf16x8*)&Bs[((wc<<6) + (j<<4) + lane16)*32 + hi8];
        #pragma unroll
        for (int i = 0; i < 4; ++i)
            #pragma unroll
            for (int j = 0; j < 4; ++j)
                acc[i][j] = __builtin_amdgcn_mfma_f32_16x16x32_bf16(af[i], bfr[j], acc[i][j], 0, 0, 0);
        __syncthreads();
    }

    #pragma unroll
    for (int i = 0; i < 4; ++i)
        #pragma unroll
        for (int r = 0; r < 4; ++r) {
            int m = bm + (wr<<6) + (i<<4) + ((l>>4)<<2) + r;
            #pragma unroll
            for (int j = 0; j < 4; ++j) {
                int n = bn + (wc<<6) + (j<<4) + lane16;
                out[((size_t)m << 10) + n] = acc[i][j][r] + bias[n];
            }
        }
}

// ---------------- sliding-window attention ----------------
// block = (b,h,q-block of 64); 4 waves x 16 queries. Window keys staged:
// [q0-64, q0+128) clamped -> NR in {128,192}; always stage 192 rows (clamped src)
// so every loop is statically unrolled; out-of-range keys mask to p=0 exactly.
__global__ __launch_bounds__(256,2) void k_attn(
    const bf16_t* __restrict__ Qr, const bf16_t* __restrict__ Kr,
    const bf16_t* __restrict__ Vh, bf16_t* __restrict__ AO)
{
    __shared__ char smem[51200];
    bf16_t* KsPs = (bf16_t*)smem;             // K window (swizzled), later aliased by P
    bf16_t* Vt   = (bf16_t*)(smem + 25600);   // V^T [64][200]

    int q0 = blockIdx.x << 6;
    int h = blockIdx.y, b_ = blockIdx.z;
    int kstart = q0 - 64; if (kstart < 0) kstart = 0;
    int kend   = q0 + 128; if (kend > 2048) kend = 2048;
    int NR = kend - kstart;                   // 128 or 192

    int tid = threadIdx.x, l = tid & 63, w = tid >> 6;
    int lane16 = l & 15, hi8 = (l >> 4) << 3;

    const bf16_t* Kbase = Kr + (((((size_t)(b_*NHEAD + h)) << 11) + kstart) << 6);
    const bf16_t* Vbase = Vh + (((((size_t)(b_*NHEAD + h)) << 11) + kstart) << 6);

    // K stage via global_load_lds; dest linear, source pre-swizzled (rule #21):
    // LDS[row][off] = K[min(row,NR-1)][off ^ ((row&7)<<4)]
    #pragma unroll
    for (int it = 0; it < 6; ++it) {
        int c = tid + (it << 8);
        int y = c << 4;                       // dest byte, 192 rows * 128B
        int row = y >> 7, oz = y & 127;
        int srow = row < NR ? row : NR - 1;
        int src = (srow << 7) + (oz ^ ((row & 7) << 4));
        gload_lds16((const char*)Kbase + src, (char*)KsPs + y);
    }
    // V stage transposed (reg path): Vt[d][j] = V[j][d]
    #pragma unroll
    for (int it = 0; it < 6; ++it) {
        int c = tid + (it << 8);
        int jd = c >> 3, d0 = (c & 7) << 3;
        int js = jd < NR ? jd : NR - 1;
        bf16x8 v8 = *(const bf16x8*)(Vbase + (js << 6) + d0);
        #pragma unroll
        for (int t = 0; t < 8; ++t) Vt[(d0 + t) * 200 + jd] = v8[t];
    }
    // Q fragments straight from global (A-frag: row=lane&15, k=(lane>>4)*8..)
    int qs = q0 + (w << 4) + lane16;
    const bf16_t* Qbase = Qr + (((((size_t)(b_*NHEAD + h)) << 11) + qs) << 6);
    bf16x8 qf0 = *(const bf16x8*)(Qbase + hi8);
    bf16x8 qf1 = *(const bf16x8*)(Qbase + 32 + hi8);

    __syncthreads();

    // scores: 12 key tiles x (K=64 -> 2 MFMA). C layout: key=lane&15, qrow=(lane>>4)*4+r
    floatx4 sc[12];
    #pragma unroll
    for (int kt = 0; kt < 12; ++kt) {
        int row = (kt << 4) + lane16;
        int base = (row << 7) + (hi8 << 1);
        int swz = (row & 7) << 4;
        bf16x8 kf0 = *(const bf16x8*)((const char*)KsPs + (base ^ swz));
        bf16x8 kf1 = *(const bf16x8*)((const char*)KsPs + ((base + 64) ^ swz));
        floatx4 a = (floatx4){0.f,0.f,0.f,0.f};
        a = __builtin_amdgcn_mfma_f32_16x16x32_bf16(qf0, kf0, a, 0, 0, 0);
        a = __builtin_amdgcn_mfma_f32_16x16x32_bf16(qf1, kf1, a, 0, 0, 0);
        sc[kt] = a;
    }

    // wave-parallel masked softmax (in registers; 16-lane group = one 4-query set)
    float inv_[4];
    #pragma unroll
    for (int r = 0; r < 4; ++r) {
        int qrow = q0 + (w << 4) + ((l >> 4) << 2) + r;
        float mx = -1e30f;
        #pragma unroll
        for (int kt = 0; kt < 12; ++kt) {
            int ks = kstart + (kt << 4) + lane16;
            int dd = qrow - ks; dd = dd < 0 ? -dd : dd;
            float sv = sc[kt][r] * 0.125f;
            sv = (dd <= 50 && ks < kend) ? sv : -1e30f;
            sc[kt][r] = sv;
            mx = fmaxf(mx, sv);
        }
        #pragma unroll
        for (int off = 1; off < 16; off <<= 1) mx = fmaxf(mx, __shfl_xor(mx, off));
        float sum = 0.f;
        #pragma unroll
        for (int kt = 0; kt < 12; ++kt) {
            float p = __expf(sc[kt][r] - mx);
            sc[kt][r] = p;
            sum += p;
        }
        #pragma unroll
        for (int off = 1; off < 16; off <<= 1) sum += __shfl_xor(sum, off);
        inv_[r] = 1.0f / sum;
    }

    __syncthreads();   // all waves done reading K window -> P may overwrite it

    // P -> per-wave LDS (A-frag layout for PV), rows padded to 200 elems
    bf16_t* Pw = KsPs + w * 16 * 200;
    #pragma unroll
    for (int r = 0; r < 4; ++r) {
        int prow = ((l >> 4) << 2) + r;
        #pragma unroll
        for (int kt = 0; kt < 12; ++kt)
            Pw[prow * 200 + (kt << 4) + lane16] = (bf16_t)(sc[kt][r] * inv_[r]);
    }

    // PV: out[16q][64d], K-dim = 192 keys -> 6 steps of 32
    floatx4 oc[4];
    #pragma unroll
    for (int dt = 0; dt < 4; ++dt) oc[dt] = (floatx4){0.f,0.f,0.f,0.f};
    #pragma unroll
    for (int ks = 0; ks < 6; ++ks) {
        bf16x8 pf = *(const bf16x8*)&Pw[lane16 * 200 + (ks << 5) + hi8];
        #pragma unroll
        for (int dt = 0; dt < 4; ++dt) {
            bf16x8 vf = *(const bf16x8*)&Vt[((dt << 4) + lane16) * 200 + (ks << 5) + hi8];
            oc[dt] = __builtin_amdgcn_mfma_f32_16x16x32_bf16(pf, vf, oc[dt], 0, 0, 0);
        }
    }
    #pragma unroll
    for (int dt = 0; dt < 4; ++dt)
        #pragma unroll
        for (int r = 0; r < 4; ++r) {
            int q = q0 + (w << 4) + ((l >> 4) << 2) + r;
            AO[(((size_t)(b_ * 2048 + q)) << 10) + (h << 6) + (dt << 4) + lane16] = (bf16_t)oc[dt][r];
        }
}

extern "C" void kernel_launch(void* const* d_in, const int* in_sizes, int n_in,
                              void* d_out, int out_size, void* d_ws, size_t ws_size,
                              hipStream_t stream)
{
    const float* query = (const float*)d_in[0];
    const float* key_  = (const float*)d_in[1];
    const float* value = (const float*)d_in[2];
    const float* Wq = (const float*)d_in[3];
    const float* bq = (const float*)d_in[4];
    const float* Wk = (const float*)d_in[5];
    const float* bk = (const float*)d_in[6];
    const float* Wv = (const float*)d_in[7];
    const float* bv = (const float*)d_in[8];
    const float* Wo = (const float*)d_in[9];
    const float* bo = (const float*)d_in[10];

    char* ws = (char*)d_ws;
    bf16_t* Xq  = (bf16_t*)(ws);
    bf16_t* Xk  = (bf16_t*)(ws + 8388608);
    bf16_t* Xv  = (bf16_t*)(ws + 16777216);
    bf16_t* Wqb = (bf16_t*)(ws + 25165824);
    bf16_t* Wkb = (bf16_t*)(ws + 27262976);
    bf16_t* Wvb = (bf16_t*)(ws + 29360128);
    bf16_t* Wob = (bf16_t*)(ws + 31457280);
    bf16_t* Qr  = (bf16_t*)(ws + 33554432);
    bf16_t* Kr  = (bf16_t*)(ws + 41943040);
    bf16_t* Vh  = (bf16_t*)(ws + 50331648);
    bf16_t* AO  = (bf16_t*)(ws + 58720256);
    float*  ct  = (float*)(ws + 67108864);
    float*  st  = (float*)(ws + 67371008);

    k_rope_table<<<256, 256, 0, stream>>>(ct, st);
    k_cvt<<<2048, 256, 0, stream>>>(query, Xq, 4194304);
    k_cvt<<<2048, 256, 0, stream>>>(key_,  Xk, 4194304);
    k_cvt<<<2048, 256, 0, stream>>>(value, Xv, 4194304);
    k_cvt<<<512, 256, 0, stream>>>(Wq, Wqb, 1048576);
    k_cvt<<<512, 256, 0, stream>>>(Wk, Wkb, 1048576);
    k_cvt<<<512, 256, 0, stream>>>(Wv, Wvb, 1048576);
    k_cvt<<<512, 256, 0, stream>>>(Wo, Wob, 1048576);
    k_gemm_qkv<<<768, 256, 0, stream>>>(Xq, Xk, Xv, Wqb, Wkb, Wvb,
                                        bq, bk, bv, Qr, Kr, Vh, ct, st);
    k_attn<<<dim3(32, 16, 2), 256, 0, stream>>>(Qr, Kr, Vh, AO);
    k_gemm_o<<<256, 256, 0, stream>>>(AO, Wob, bo, (float*)d_out);
}

// Round 2
// 97.607 us; speedup vs baseline: 1.2056x; 1.2056x over previous
//
#include <hip/hip_runtime.h>
#include <hip/hip_bf16.h>
#include <math.h>

typedef __bf16 bf16_t;
typedef __bf16 bf16x8 __attribute__((ext_vector_type(8)));
typedef float floatx4 __attribute__((ext_vector_type(4)));
typedef unsigned int u32;

#define NHEAD 16

// async global->LDS, 16B per lane. Dest must be wave-uniform base + lane*16.
__device__ __forceinline__ void gload_lds16(const void* g, void* l) {
    __builtin_amdgcn_global_load_lds((const __attribute__((address_space(1))) u32*)g,
                                     (__attribute__((address_space(3))) u32*)l, 16, 0, 0);
}

// ---------------- fused prep: fp32->bf16 converts (7 tensors) + RoPE table ----------------
// blocks [0,8192): converts, 8 elems/thread. blocks [8192,8448): rope table.
__global__ __launch_bounds__(256) void k_prep(
    const float* __restrict__ q, const float* __restrict__ k, const float* __restrict__ v,
    const float* __restrict__ wq, const float* __restrict__ wk,
    const float* __restrict__ wv, const float* __restrict__ wo,
    bf16_t* __restrict__ Xq, bf16_t* __restrict__ Xk, bf16_t* __restrict__ Xv,
    bf16_t* __restrict__ Wqb, bf16_t* __restrict__ Wkb, bf16_t* __restrict__ Wvb,
    bf16_t* __restrict__ Wob, float* __restrict__ ct, float* __restrict__ st)
{
    int b = blockIdx.x;
    if (b < 8192) {
        const float* src; bf16_t* dst; int off;
        if      (b < 2048) { src = q;  dst = Xq;  off = b; }
        else if (b < 4096) { src = k;  dst = Xk;  off = b - 2048; }
        else if (b < 6144) { src = v;  dst = Xv;  off = b - 4096; }
        else if (b < 6656) { src = wq; dst = Wqb; off = b - 6144; }
        else if (b < 7168) { src = wk; dst = Wkb; off = b - 6656; }
        else if (b < 7680) { src = wv; dst = Wvb; off = b - 7168; }
        else               { src = wo; dst = Wob; off = b - 7680; }
        int i = (off * 256 + threadIdx.x) * 8;
        float4 a = *(const float4*)(src + i);
        float4 c = *(const float4*)(src + i + 4);
        bf16x8 o;
        o[0]=(bf16_t)a.x; o[1]=(bf16_t)a.y; o[2]=(bf16_t)a.z; o[3]=(bf16_t)a.w;
        o[4]=(bf16_t)c.x; o[5]=(bf16_t)c.y; o[6]=(bf16_t)c.z; o[7]=(bf16_t)c.w;
        *(bf16x8*)(dst + i) = o;
    } else {
        int idx = (b - 8192) * 256 + threadIdx.x;   // 65536 = 2048*32
        int s = idx >> 5, i = idx & 31;
        float e = (float)(2 * i) / 64.0f;
        float invf = 1.0f / powf(10000.0f, e);
        float ang = (float)s * invf;
        ct[idx] = cosf(ang);
        st[idx] = sinf(ang);
    }
}

// ---------------- QKV GEMM: 128x128 tile, BK=32, 2-phase dbuf prefetch ----------------
// out[m,n] = sum_k A[m,k]*W[n,k] + b[n]; epilogue -> [B,H,S,64] bf16 with RoPE for Q,K.
__global__ __launch_bounds__(256,2) void k_gemm_qkv(
    const bf16_t* __restrict__ Xq, const bf16_t* __restrict__ Xk, const bf16_t* __restrict__ Xv,
    const bf16_t* __restrict__ Wqb, const bf16_t* __restrict__ Wkb, const bf16_t* __restrict__ Wvb,
    const float* __restrict__ bq, const float* __restrict__ bk, const float* __restrict__ bv,
    bf16_t* __restrict__ Qr, bf16_t* __restrict__ Kr, bf16_t* __restrict__ Vh,
    const float* __restrict__ ct, const float* __restrict__ st)
{
    __shared__ bf16_t As[2][128*32];
    __shared__ bf16_t Bs[2][128*32];

    // XCD-aware swizzle: 768 logical wgs, 96-chunk per XCD (768%8==0 -> simple form)
    int b0 = blockIdx.x;
    int wg = (b0 & 7) * 96 + (b0 >> 3);
    int id  = wg >> 8;                  // 0=Q 1=K 2=V
    int bid = wg & 255;

    const bf16_t* A   = (id==0) ? Xq  : (id==1) ? Xk  : Xv;
    const bf16_t* Wt  = (id==0) ? Wqb : (id==1) ? Wkb : Wvb;
    const float*  bias= (id==0) ? bq  : (id==1) ? bk  : bv;
    bf16_t* out = (id==0) ? Qr : (id==1) ? Kr : Vh;
    bool do_rope = (id < 2);

    int bm = (bid >> 3) << 7;           // M=4096 -> 32 row tiles
    int bn = (bid & 7) << 7;            // N=1024 -> 8 col tiles
    int tid = threadIdx.x;
    int l = tid & 63, wid = tid >> 6;
    int wr = wid >> 1, wc = wid & 1;
    int lane16 = l & 15, hi8 = (l >> 4) << 3;

    floatx4 acc[4][4];
    #pragma unroll
    for (int i = 0; i < 4; ++i)
        #pragma unroll
        for (int j = 0; j < 4; ++j) acc[i][j] = (floatx4){0.f,0.f,0.f,0.f};

    int srow = tid >> 2, scol = (tid & 3) << 3;   // staging coords (rows 0..63 + 64..127)
    const bf16_t* Ab = A  + ((size_t)(bm + srow) << 10) + scol;
    const bf16_t* Bb = Wt + ((size_t)(bn + srow) << 10) + scol;

    // prologue: stage tile 0 into buffer 0
    #pragma unroll
    for (int i2 = 0; i2 < 2; ++i2) {
        gload_lds16(Ab + (i2 << 16), &As[0][(tid + (i2<<8)) << 3]);
        gload_lds16(Bb + (i2 << 16), &Bs[0][(tid + (i2<<8)) << 3]);
    }
    __syncthreads();

    int cur = 0;
    for (int t = 0; t < 32; ++t) {
        if (t < 31) {          // prefetch tile t+1 into other buffer (in flight across MFMA)
            int k0 = (t + 1) << 5;
            #pragma unroll
            for (int i2 = 0; i2 < 2; ++i2) {
                gload_lds16(Ab + k0 + (i2 << 16), &As[cur^1][(tid + (i2<<8)) << 3]);
                gload_lds16(Bb + k0 + (i2 << 16), &Bs[cur^1][(tid + (i2<<8)) << 3]);
            }
        }
        bf16x8 af[4], bfr[4];
        #pragma unroll
        for (int i = 0; i < 4; ++i)
            af[i]  = *(const bf16x8*)&As[cur][((wr<<6) + (i<<4) + lane16)*32 + hi8];
        #pragma unroll
        for (int j = 0; j < 4; ++j)
            bfr[j] = *(const bf16x8*)&Bs[cur][((wc<<6) + (j<<4) + lane16)*32 + hi8];
        #pragma unroll
        for (int i = 0; i < 4; ++i)
            #pragma unroll
            for (int j = 0; j < 4; ++j)
                acc[i][j] = __builtin_amdgcn_mfma_f32_16x16x32_bf16(af[i], bfr[j], acc[i][j], 0, 0, 0);
        __syncthreads();       // drains vmcnt(0) AFTER compute: prefetch had MFMA phase to land
        cur ^= 1;
    }

    int h = (bn + (wc<<6)) >> 6;        // head index (64-wide wave tile == one head)
    #pragma unroll
    for (int i = 0; i < 4; ++i) {
        #pragma unroll
        for (int r = 0; r < 4; ++r) {
            int m  = bm + (wr<<6) + (i<<4) + ((l>>4)<<2) + r;
            int b_ = m >> 11, s_ = m & 2047;
            size_t ob = ((((size_t)(b_*NHEAD + h)) << 11) + s_) << 6;
            if (do_rope) {
                #pragma unroll
                for (int j = 0; j < 2; ++j) {
                    int d = (j<<4) + lane16;                 // 0..31
                    float lo = acc[i][j][r]   + bias[bn + (wc<<6) + d];
                    float hv = acc[i][j+2][r] + bias[bn + (wc<<6) + d + 32];
                    float c = ct[(s_<<5) + d], sn = st[(s_<<5) + d];
                    out[ob + d]      = (bf16_t)(lo*c - hv*sn);
                    out[ob + d + 32] = (bf16_t)(hv*c + lo*sn);
                }
            } else {
                #pragma unroll
                for (int j = 0; j < 4; ++j) {
                    int d = (j<<4) + lane16;
                    out[ob + d] = (bf16_t)(acc[i][j][r] + bias[bn + (wc<<6) + d]);
                }
            }
        }
    }
}

// ---------------- O GEMM: fp32 [4096][1024] output, same 2-phase structure ----------------
__global__ __launch_bounds__(256,2) void k_gemm_o(
    const bf16_t* __restrict__ A, const bf16_t* __restrict__ Wt,
    const float* __restrict__ bias, float* __restrict__ out)
{
    __shared__ bf16_t As[2][128*32];
    __shared__ bf16_t Bs[2][128*32];

    int b0 = blockIdx.x;
    int bid = (b0 & 7) * 32 + (b0 >> 3);   // 256 wgs, 32-chunk per XCD
    int bm = (bid >> 3) << 7;
    int bn = (bid & 7) << 7;
    int tid = threadIdx.x;
    int l = tid & 63, wid = tid >> 6;
    int wr = wid >> 1, wc = wid & 1;
    int lane16 = l & 15, hi8 = (l >> 4) << 3;

    floatx4 acc[4][4];
    #pragma unroll
    for (int i = 0; i < 4; ++i)
        #pragma unroll
        for (int j = 0; j < 4; ++j) acc[i][j] = (floatx4){0.f,0.f,0.f,0.f};

    int srow = tid >> 2, scol = (tid & 3) << 3;
    const bf16_t* Ab = A  + ((size_t)(bm + srow) << 10) + scol;
    const bf16_t* Bb = Wt + ((size_t)(bn + srow) << 10) + scol;

    #pragma unroll
    for (int i2 = 0; i2 < 2; ++i2) {
        gload_lds16(Ab + (i2 << 16), &As[0][(tid + (i2<<8)) << 3]);
        gload_lds16(Bb + (i2 << 16), &Bs[0][(tid + (i2<<8)) << 3]);
    }
    __syncthreads();

    int cur = 0;
    for (int t = 0; t < 32; ++t) {
        if (t < 31) {
            int k0 = (t + 1) << 5;
            #pragma unroll
            for (int i2 = 0; i2 < 2; ++i2) {
                gload_lds16(Ab + k0 + (i2 << 16), &As[cur^1][(tid + (i2<<8)) << 3]);
                gload_lds16(Bb + k0 + (i2 << 16), &Bs[cur^1][(tid + (i2<<8)) << 3]);
            }
        }
        bf16x8 af[4], bfr[4];
        #pragma unroll
        for (int i = 0; i < 4; ++i)
            af[i]  = *(const bf16x8*)&As[cur][((wr<<6) + (i<<4) + lane16)*32 + hi8];
        #pragma unroll
        for (int j = 0; j < 4; ++j)
            bfr[j] = *(const bf16x8*)&Bs[cur][((wc<<6) + (j<<4) + lane16)*32 + hi8];
        #pragma unroll
        for (int i = 0; i < 4; ++i)
            #pragma unroll
            for (int j = 0; j < 4; ++j)
                acc[i][j] = __builtin_amdgcn_mfma_f32_16x16x32_bf16(af[i], bfr[j], acc[i][j], 0, 0, 0);
        __syncthreads();
        cur ^= 1;
    }

    #pragma unroll
    for (int i = 0; i < 4; ++i)
        #pragma unroll
        for (int r = 0; r < 4; ++r) {
            int m = bm + (wr<<6) + (i<<4) + ((l>>4)<<2) + r;
            #pragma unroll
            for (int j = 0; j < 4; ++j) {
                int n = bn + (wc<<6) + (j<<4) + lane16;
                out[((size_t)m << 10) + n] = acc[i][j][r] + bias[n];
            }
        }
}

// ---------------- sliding-window attention (unchanged from R0) ----------------
__global__ __launch_bounds__(256,2) void k_attn(
    const bf16_t* __restrict__ Qr, const bf16_t* __restrict__ Kr,
    const bf16_t* __restrict__ Vh, bf16_t* __restrict__ AO)
{
    __shared__ char smem[51200];
    bf16_t* KsPs = (bf16_t*)smem;             // K window (swizzled), later aliased by P
    bf16_t* Vt   = (bf16_t*)(smem + 25600);   // V^T [64][200]

    int q0 = blockIdx.x << 6;
    int h = blockIdx.y, b_ = blockIdx.z;
    int kstart = q0 - 64; if (kstart < 0) kstart = 0;
    int kend   = q0 + 128; if (kend > 2048) kend = 2048;
    int NR = kend - kstart;                   // 128 or 192

    int tid = threadIdx.x, l = tid & 63, w = tid >> 6;
    int lane16 = l & 15, hi8 = (l >> 4) << 3;

    const bf16_t* Kbase = Kr + (((((size_t)(b_*NHEAD + h)) << 11) + kstart) << 6);
    const bf16_t* Vbase = Vh + (((((size_t)(b_*NHEAD + h)) << 11) + kstart) << 6);

    // K stage via global_load_lds; dest linear, source pre-swizzled (rule #21)
    #pragma unroll
    for (int it = 0; it < 6; ++it) {
        int c = tid + (it << 8);
        int y = c << 4;                       // dest byte, 192 rows * 128B
        int row = y >> 7, oz = y & 127;
        int srw = row < NR ? row : NR - 1;
        int src = (srw << 7) + (oz ^ ((row & 7) << 4));
        gload_lds16((const char*)Kbase + src, (char*)KsPs + y);
    }
    // V stage transposed (reg path): Vt[d][j] = V[j][d]
    #pragma unroll
    for (int it = 0; it < 6; ++it) {
        int c = tid + (it << 8);
        int jd = c >> 3, d0 = (c & 7) << 3;
        int js = jd < NR ? jd : NR - 1;
        bf16x8 v8 = *(const bf16x8*)(Vbase + (js << 6) + d0);
        #pragma unroll
        for (int t = 0; t < 8; ++t) Vt[(d0 + t) * 200 + jd] = v8[t];
    }
    int qs = q0 + (w << 4) + lane16;
    const bf16_t* Qbase = Qr + (((((size_t)(b_*NHEAD + h)) << 11) + qs) << 6);
    bf16x8 qf0 = *(const bf16x8*)(Qbase + hi8);
    bf16x8 qf1 = *(const bf16x8*)(Qbase + 32 + hi8);

    __syncthreads();

    floatx4 sc[12];
    #pragma unroll
    for (int kt = 0; kt < 12; ++kt) {
        int row = (kt << 4) + lane16;
        int base = (row << 7) + (hi8 << 1);
        int swz = (row & 7) << 4;
        bf16x8 kf0 = *(const bf16x8*)((const char*)KsPs + (base ^ swz));
        bf16x8 kf1 = *(const bf16x8*)((const char*)KsPs + ((base + 64) ^ swz));
        floatx4 a = (floatx4){0.f,0.f,0.f,0.f};
        a = __builtin_amdgcn_mfma_f32_16x16x32_bf16(qf0, kf0, a, 0, 0, 0);
        a = __builtin_amdgcn_mfma_f32_16x16x32_bf16(qf1, kf1, a, 0, 0, 0);
        sc[kt] = a;
    }

    float inv_[4];
    #pragma unroll
    for (int r = 0; r < 4; ++r) {
        int qrow = q0 + (w << 4) + ((l >> 4) << 2) + r;
        float mx = -1e30f;
        #pragma unroll
        for (int kt = 0; kt < 12; ++kt) {
            int ks = kstart + (kt << 4) + lane16;
            int dd = qrow - ks; dd = dd < 0 ? -dd : dd;
            float sv = sc[kt][r] * 0.125f;
            sv = (dd <= 50 && ks < kend) ? sv : -1e30f;
            sc[kt][r] = sv;
            mx = fmaxf(mx, sv);
        }
        #pragma unroll
        for (int off = 1; off < 16; off <<= 1) mx = fmaxf(mx, __shfl_xor(mx, off));
        float sum = 0.f;
        #pragma unroll
        for (int kt = 0; kt < 12; ++kt) {
            float p = __expf(sc[kt][r] - mx);
            sc[kt][r] = p;
            sum += p;
        }
        #pragma unroll
        for (int off = 1; off < 16; off <<= 1) sum += __shfl_xor(sum, off);
        inv_[r] = 1.0f / sum;
    }

    __syncthreads();   // all waves done reading K window -> P may overwrite it

    bf16_t* Pw = KsPs + w * 16 * 200;
    #pragma unroll
    for (int r = 0; r < 4; ++r) {
        int prow = ((l >> 4) << 2) + r;
        #pragma unroll
        for (int kt = 0; kt < 12; ++kt)
            Pw[prow * 200 + (kt << 4) + lane16] = (bf16_t)(sc[kt][r] * inv_[r]);
    }

    floatx4 oc[4];
    #pragma unroll
    for (int dt = 0; dt < 4; ++dt) oc[dt] = (floatx4){0.f,0.f,0.f,0.f};
    #pragma unroll
    for (int ks = 0; ks < 6; ++ks) {
        bf16x8 pf = *(const bf16x8*)&Pw[lane16 * 200 + (ks << 5) + hi8];
        #pragma unroll
        for (int dt = 0; dt < 4; ++dt) {
            bf16x8 vf = *(const bf16x8*)&Vt[((dt << 4) + lane16) * 200 + (ks << 5) + hi8];
            oc[dt] = __builtin_amdgcn_mfma_f32_16x16x32_bf16(pf, vf, oc[dt], 0, 0, 0);
        }
    }
    #pragma unroll
    for (int dt = 0; dt < 4; ++dt)
        #pragma unroll
        for (int r = 0; r < 4; ++r) {
            int qq = q0 + (w << 4) + ((l >> 4) << 2) + r;
            AO[(((size_t)(b_ * 2048 + qq)) << 10) + (h << 6) + (dt << 4) + lane16] = (bf16_t)oc[dt][r];
        }
}

extern "C" void kernel_launch(void* const* d_in, const int* in_sizes, int n_in,
                              void* d_out, int out_size, void* d_ws, size_t ws_size,
                              hipStream_t stream)
{
    const float* query = (const float*)d_in[0];
    const float* key_  = (const float*)d_in[1];
    const float* value = (const float*)d_in[2];
    const float* Wq = (const float*)d_in[3];
    const float* bq = (const float*)d_in[4];
    const float* Wk = (const float*)d_in[5];
    const float* bk = (const float*)d_in[6];
    const float* Wv = (const float*)d_in[7];
    const float* bv = (const float*)d_in[8];
    const float* Wo = (const float*)d_in[9];
    const float* bo = (const float*)d_in[10];

    char* ws = (char*)d_ws;
    bf16_t* Xq  = (bf16_t*)(ws);
    bf16_t* Xk  = (bf16_t*)(ws + 8388608);
    bf16_t* Xv  = (bf16_t*)(ws + 16777216);
    bf16_t* Wqb = (bf16_t*)(ws + 25165824);
    bf16_t* Wkb = (bf16_t*)(ws + 27262976);
    bf16_t* Wvb = (bf16_t*)(ws + 29360128);
    bf16_t* Wob = (bf16_t*)(ws + 31457280);
    bf16_t* Qr  = (bf16_t*)(ws + 33554432);
    bf16_t* Kr  = (bf16_t*)(ws + 41943040);
    bf16_t* Vh  = (bf16_t*)(ws + 50331648);
    bf16_t* AO  = (bf16_t*)(ws + 58720256);
    float*  ct  = (float*)(ws + 67108864);
    float*  st  = (float*)(ws + 67371008);

    k_prep<<<8448, 256, 0, stream>>>(query, key_, value, Wq, Wk, Wv, Wo,
                                     Xq, Xk, Xv, Wqb, Wkb, Wvb, Wob, ct, st);
    k_gemm_qkv<<<768, 256, 0, stream>>>(Xq, Xk, Xv, Wqb, Wkb, Wvb,
                                        bq, bk, bv, Qr, Kr, Vh, ct, st);
    k_attn<<<dim3(32, 16, 2), 256, 0, stream>>>(Qr, Kr, Vh, AO);
    k_gemm_o<<<256, 256, 0, stream>>>(AO, Wob, bo, (float*)d_out);
}